// Round 7
// baseline (386.907 us; speedup 1.0000x reference)
//
#include <hip/hip_runtime.h>
#include <hip/hip_cooperative_groups.h>
#include <math.h>

namespace cg = cooperative_groups;

#define L_ 2048
#define D_ 512
#define K_ 64

typedef __attribute__((ext_vector_type(8))) short short8;
typedef __attribute__((ext_vector_type(4))) float f32x4;
typedef __attribute__((ext_vector_type(4))) unsigned short us4;

__device__ __forceinline__ unsigned short f2bf(float f) {
    unsigned int u = __builtin_bit_cast(unsigned int, f);
    u += 0x7fffu + ((u >> 16) & 1u);   // RNE
    return (unsigned short)(u >> 16);
}
__device__ __forceinline__ float bf2f(unsigned int u) {
    return __builtin_bit_cast(float, u << 16);
}
__device__ __forceinline__ f32x4 MFMA(short8 a, short8 b, f32x4 c) {
    return __builtin_amdgcn_mfma_f32_16x16x32_bf16(a, b, c, 0, 0, 0);
}

enum { EPI_BIAS = 0, EPI_GELU = 1, EPI_AMP = 2, EPI_OUT = 4 };

struct Params {
    const float *x, *ke_w1, *ke_b1, *ke_w2, *ke_b2, *qe_w1, *qe_b1, *qe_w2, *qe_b2;
    const float *amp_w, *amp_b, *v_w, *v_b, *ln_g, *ln_b, *out_w, *out_b;
    float* out;
    unsigned short *xb, *hk, *hq, *Vb, *Vt, *Qp, *Kp, *rnb;
    float* amp;
    unsigned short *wtke1, *wtqe1, *wtv, *wtout, *wtke2, *wtqe2, *wtamp;
    unsigned short* P;
    int ng;
};

// ---------- LDS-free bf16 MFMA GEMM: 64x64 tile, fragments direct from global ----------
// A [M][512], Bt [N][512]; both fragment layouts are contiguous 16B row segments.
template<int EPI>
__device__ __forceinline__ void gemm_direct(
    const unsigned short* __restrict__ A, const unsigned short* __restrict__ Bt,
    const float* __restrict__ bias, int N, int m0, int n0,
    unsigned short* __restrict__ Cb, float* __restrict__ Cf,
    const float* __restrict__ extra)
{
    const int KD = 512;
    const int t = threadIdx.x;
    const int w = t >> 6, lane = t & 63, n_ = lane & 15, quad = lane >> 4;
    const int mh = (w >> 1) * 32, nh = (w & 1) * 32;

    f32x4 acc[2][2];
#pragma unroll
    for (int i = 0; i < 2; i++)
#pragma unroll
        for (int j = 0; j < 2; j++) acc[i][j] = (f32x4){0.f, 0.f, 0.f, 0.f};

    const unsigned short* a0p = &A[(size_t)(m0 + mh + n_) * KD + quad * 8];
    const unsigned short* a1p = a0p + 16 * KD;
    const unsigned short* b0p = &Bt[(size_t)(n0 + nh + n_) * KD + quad * 8];
    const unsigned short* b1p = b0p + 16 * KD;

#pragma unroll 2
    for (int k0 = 0; k0 < KD; k0 += 32) {
        short8 a0 = *(const short8*)(a0p + k0);
        short8 a1 = *(const short8*)(a1p + k0);
        short8 b0 = *(const short8*)(b0p + k0);
        short8 b1 = *(const short8*)(b1p + k0);
        acc[0][0] = MFMA(a0, b0, acc[0][0]);
        acc[0][1] = MFMA(a0, b1, acc[0][1]);
        acc[1][0] = MFMA(a1, b0, acc[1][0]);
        acc[1][1] = MFMA(a1, b1, acc[1][1]);
    }

#pragma unroll
    for (int i = 0; i < 2; i++) {
#pragma unroll
        for (int j = 0; j < 2; j++) {
            const int mb = m0 + mh + i * 16 + quad * 4;
            const int nb = n0 + nh + j * 16 + n_;
            const float bsv = bias[nb];
#pragma unroll
            for (int reg = 0; reg < 4; reg++) {
                const int m = mb + reg;
                float v = acc[i][j][reg] + bsv;
                if (EPI == EPI_GELU) {
                    v = 0.5f * v * (1.0f + erff(v * 0.70710678118654752f));
                    Cb[(size_t)m * N + nb] = f2bf(v);
                } else if (EPI == EPI_BIAS) {
                    Cb[(size_t)m * N + nb] = f2bf(v);
                } else if (EPI == EPI_AMP) {
                    float u = (v > 20.f) ? v : log1pf(expf(v));
                    Cf[(size_t)m * N + nb] = u + 0.1f;
                } else { // EPI_OUT
                    Cf[(size_t)m * N + nb] = v + extra[(size_t)m * N + nb];
                }
            }
        }
    }
}

// ---------- LDS-free phase GEMM: 32x64 tile (N=64), phase epilogue ----------
__device__ __forceinline__ void phase_direct(
    const unsigned short* __restrict__ A, const unsigned short* __restrict__ Bt,
    const float* __restrict__ bias, int m0,
    unsigned short* __restrict__ Cb, const float* __restrict__ amp)
{
    const int KD = 512;
    const int t = threadIdx.x;
    const int w = t >> 6, lane = t & 63, n_ = lane & 15, quad = lane >> 4;

    f32x4 acc[2];
    acc[0] = (f32x4){0.f, 0.f, 0.f, 0.f};
    acc[1] = (f32x4){0.f, 0.f, 0.f, 0.f};

    const unsigned short* a0p = &A[(size_t)(m0 + n_) * KD + quad * 8];
    const unsigned short* a1p = a0p + 16 * KD;
    const unsigned short* bp  = &Bt[(size_t)(w * 16 + n_) * KD + quad * 8];

#pragma unroll 2
    for (int k0 = 0; k0 < KD; k0 += 32) {
        short8 a0 = *(const short8*)(a0p + k0);
        short8 a1 = *(const short8*)(a1p + k0);
        short8 b  = *(const short8*)(bp + k0);
        acc[0] = MFMA(a0, b, acc[0]);
        acc[1] = MFMA(a1, b, acc[1]);
    }

    const int nb = w * 16 + n_;
    const float bsv = bias[nb];
#pragma unroll
    for (int i = 0; i < 2; i++) {
        const int mb = m0 + i * 16 + quad * 4;
#pragma unroll
        for (int reg = 0; reg < 4; reg++) {
            const int m = mb + reg;
            float v = acc[i][reg] + bsv;
            float am = amp[(size_t)m * 64 + nb];
            float p = tanhf(v) * 3.14159265358979323846f;
            float sp, cp; sincosf(p, &sp, &cp);
            Cb[(size_t)m * 128 + nb]      = f2bf(am * cp);
            Cb[(size_t)m * 128 + 64 + nb] = f2bf(am * sp);
        }
    }
}

// ---------- weight transpose item: S[R=512][C] fp32 -> D[C][512] bf16 (4224 B LDS) ----
__device__ __forceinline__ void transp_item(const float* S, unsigned short* D, int C,
                                            int c0, int r0, unsigned short* lds)
{
    float (*tile)[33] = (float (*)[33])lds;
    const int t = threadIdx.x, r = t >> 3, c4 = (t & 7) * 4;
    float4 v = *(const float4*)&S[(size_t)(r0 + r) * C + c0 + c4];
    tile[r][c4 + 0] = v.x; tile[r][c4 + 1] = v.y;
    tile[r][c4 + 2] = v.z; tile[r][c4 + 3] = v.w;
    __syncthreads();
    us4 o;
    o.x = f2bf(tile[c4 + 0][r]); o.y = f2bf(tile[c4 + 1][r]);
    o.z = f2bf(tile[c4 + 2][r]); o.w = f2bf(tile[c4 + 3][r]);
    *(us4*)&D[(size_t)(c0 + r) * 512 + r0 + c4] = o;
    __syncthreads();   // LDS reuse hazard across items
}

__device__ __forceinline__ void prep_item(const Params& p, int it, unsigned short* lds)
{
    const int t = threadIdx.x;
    if (it < 1024) {
        const int z = it >> 8, sub = it & 255;
        const int c0 = (sub & 15) * 32, r0 = (sub >> 4) * 32;
        const float* S; unsigned short* D;
        switch (z) {
            case 0: S = p.ke_w1; D = p.wtke1; break;
            case 1: S = p.qe_w1; D = p.wtqe1; break;
            case 2: S = p.v_w;   D = p.wtv;   break;
            default: S = p.out_w; D = p.wtout; break;
        }
        transp_item(S, D, 512, c0, r0, lds);
    } else if (it < 1120) {
        const int rel = it - 1024, z = rel >> 5, sub = rel & 31;
        const int c0 = (sub & 1) * 32, r0 = (sub >> 1) * 32;
        const float* S; unsigned short* D;
        switch (z) {
            case 0: S = p.ke_w2; D = p.wtke2; break;
            case 1: S = p.qe_w2; D = p.wtqe2; break;
            default: S = p.amp_w; D = p.wtamp; break;
        }
        transp_item(S, D, 64, c0, r0, lds);
    } else {
        const int b = it - 1120;     // 0..255, x cast
        const float4* src = (const float4*)p.x;
#pragma unroll
        for (int j = 0; j < 4; j++) {
            const int idx = b * 1024 + j * 256 + t;
            float4 v = src[idx];
            us4 o;
            o.x = f2bf(v.x); o.y = f2bf(v.y); o.z = f2bf(v.z); o.w = f2bf(v.w);
            *(us4*)&p.xb[(size_t)idx * 4] = o;
        }
    }
}

__device__ __forceinline__ void qkva_item(const Params& p, int b)
{
    if (b < 768) {
        const int which = b >> 8, wi = b & 255;
        const int m0 = (wi & 31) * 64, n0 = (wi >> 5) * 64;
        if (which == 0)
            gemm_direct<EPI_GELU>(p.xb, p.wtke1, p.ke_b1, 512, m0, n0, p.hk, nullptr, nullptr);
        else if (which == 1)
            gemm_direct<EPI_GELU>(p.xb, p.wtqe1, p.qe_b1, 512, m0, n0, p.hq, nullptr, nullptr);
        else
            gemm_direct<EPI_BIAS>(p.xb, p.wtv, p.v_b, 512, m0, n0, p.Vb, nullptr, nullptr);
    } else {
        const int m0 = (b - 768) * 64;
        gemm_direct<EPI_AMP>(p.xb, p.wtamp, p.amp_b, 64, m0, 0, nullptr, p.amp, nullptr);
    }
}

__device__ __forceinline__ void phtv_item(const Params& p, int b, unsigned short* lds)
{
    if (b < 128) {
        if (b < 64)
            phase_direct(p.hk, p.wtke2, p.ke_b2, b * 32, p.Kp, p.amp);
        else
            phase_direct(p.hq, p.wtqe2, p.qe_b2, (b - 64) * 32, p.Qp, p.amp);
    } else {
        const int bb = b - 128;
        const int c0 = (bb & 15) * 32, r0 = (bb >> 4) * 32;
        unsigned short (*tile)[33] = (unsigned short (*)[33])lds;
        const int t = threadIdx.x, r = t >> 3, c4 = (t & 7) * 4;
        us4 v = *(const us4*)&p.Vb[(size_t)(r0 + r) * 512 + c0 + c4];
        tile[r][c4 + 0] = v.x; tile[r][c4 + 1] = v.y;
        tile[r][c4 + 2] = v.z; tile[r][c4 + 3] = v.w;
        __syncthreads();
        us4 o;
        o.x = tile[c4 + 0][r]; o.y = tile[c4 + 1][r];
        o.z = tile[c4 + 2][r]; o.w = tile[c4 + 3][r];
        *(us4*)&p.Vt[(size_t)(c0 + r) * 2048 + r0 + c4] = o;
        __syncthreads();
    }
}

__device__ __forceinline__ void attm_item(const Params& p, int item, unsigned short* lds)
{
    unsigned short* Ss = lds;    // 32*56 shorts = 3584 B
    const int ng = p.ng;
    const int g = item % ng, lt = item / ng;
    const int l0 = lt * 32;
    const int t = threadIdx.x;
    const int w = t >> 6, lane = t & 63, n_ = lane & 15, quad = lane >> 4;
    const int lh = (w >> 1) * 16, th = (w & 1) * 16;

    short8 qf[4];
    {
        const unsigned short* qrow = &p.Qp[(size_t)(l0 + lh + n_) * 128 + quad * 8];
#pragma unroll
        for (int kc = 0; kc < 4; kc++) qf[kc] = *(const short8*)(qrow + kc * 32);
    }

    f32x4 acc[2][8];
#pragma unroll
    for (int i = 0; i < 2; i++)
#pragma unroll
        for (int j = 0; j < 8; j++) acc[i][j] = (f32x4){0.f, 0.f, 0.f, 0.f};

    for (int tile = g; tile <= lt; tile += ng) {
        const int t0 = tile * 32;
        const unsigned short* krow = &p.Kp[(size_t)(t0 + th + n_) * 128 + quad * 8];
        f32x4 s = (f32x4){0.f, 0.f, 0.f, 0.f};
#pragma unroll
        for (int kc = 0; kc < 4; kc++)
            s = MFMA(qf[kc], *(const short8*)(krow + kc * 32), s);

        const int lrow = lh + quad * 4;
        if (tile == lt) {
            const int tg = t0 + th + n_;
#pragma unroll
            for (int reg = 0; reg < 4; reg++) {
                float v = (tg <= l0 + lrow + reg) ? s[reg] : 0.f;
                Ss[(lrow + reg) * 56 + th + n_] = f2bf(v);
            }
        } else {
#pragma unroll
            for (int reg = 0; reg < 4; reg++)
                Ss[(lrow + reg) * 56 + th + n_] = f2bf(s[reg]);
        }
        __syncthreads();

        short8 sa0 = *(const short8*)&Ss[n_ * 56 + quad * 8];
        short8 sa1 = *(const short8*)&Ss[(16 + n_) * 56 + quad * 8];
        const unsigned short* vrow = &p.Vt[(size_t)(w * 128 + n_) * 2048 + t0 + quad * 8];
#pragma unroll
        for (int jc = 0; jc < 8; jc++) {
            short8 vf = *(const short8*)(vrow + (size_t)jc * 16 * 2048);
            acc[0][jc] = MFMA(sa0, vf, acc[0][jc]);
            acc[1][jc] = MFMA(sa1, vf, acc[1][jc]);
        }
        __syncthreads();
    }

    unsigned short* Pg = &p.P[((size_t)g * L_ + l0) * 512];
#pragma unroll
    for (int i = 0; i < 2; i++) {
#pragma unroll
        for (int jc = 0; jc < 8; jc++) {
            const int row = i * 16 + quad * 4;
            const int d = w * 128 + jc * 16 + n_;
#pragma unroll
            for (int reg = 0; reg < 4; reg++)
                Pg[(size_t)(row + reg) * 512 + d] = f2bf(acc[i][jc][reg]);
        }
    }
}

__device__ __forceinline__ void redln_item(const Params& p, int l, unsigned short* lds)
{
    float* sb = (float*)lds;
    const int t = threadIdx.x;
    float rx = 0.f, ry = 0.f;
    for (int gi = 0; gi < p.ng; gi++) {
        unsigned int pk = *(const unsigned int*)&p.P[((size_t)gi * L_ + l) * 512 + 2 * t];
        rx += bf2f(pk & 0xffffu);
        ry += bf2f(pk >> 16);
    }
    const float scale = rsqrtf((float)((l + 1) * K_));
    rx *= scale; ry *= scale;

    float s = rx + ry, s2 = rx * rx + ry * ry;
#pragma unroll
    for (int o = 32; o > 0; o >>= 1) {
        s  += __shfl_down(s,  o);
        s2 += __shfl_down(s2, o);
    }
    if ((t & 63) == 0) { int wv = t >> 6; sb[wv] = s; sb[4 + wv] = s2; }
    __syncthreads();
    s  = sb[0] + sb[1] + sb[2] + sb[3];
    s2 = sb[4] + sb[5] + sb[6] + sb[7];

    const float mu   = s * (1.f / 512.f);
    const float var  = s2 * (1.f / 512.f) - mu * mu;
    const float rstd = rsqrtf(var + 1e-5f);

    const int d = t << 1;
    p.rnb[(size_t)l * 512 + d]     = f2bf((rx - mu) * rstd * p.ln_g[d]     + p.ln_b[d]);
    p.rnb[(size_t)l * 512 + d + 1] = f2bf((ry - mu) * rstd * p.ln_g[d + 1] + p.ln_b[d + 1]);
    __syncthreads();   // sb reuse hazard across items
}

__device__ __forceinline__ void outg_item(const Params& p, int it)
{
    const int m0 = (it & 31) * 64, n0 = (it >> 5) * 64;
    gemm_direct<EPI_OUT>(p.rnb, p.wtout, p.out_b, 512, m0, n0, nullptr, p.out, p.x);
}

// =================== cooperative megakernel (LDS = 4224 B) ===================
__global__ void __launch_bounds__(256) mega_k(Params p)
{
    __shared__ __align__(16) unsigned short lds[2112];   // 4224 B
    cg::grid_group grid = cg::this_grid();
    const int G = gridDim.x;

    for (int it = blockIdx.x; it < 1376; it += G) prep_item(p, it, lds);
    grid.sync();
    for (int it = blockIdx.x; it < 800; it += G) qkva_item(p, it);
    grid.sync();
    for (int it = blockIdx.x; it < 1152; it += G) phtv_item(p, it, lds);
    grid.sync();
    for (int it = blockIdx.x; it < p.ng * 64; it += G) attm_item(p, it, lds);
    __threadfence();
    grid.sync();
    for (int it = blockIdx.x; it < 2048; it += G) redln_item(p, it, lds);
    grid.sync();
    for (int it = blockIdx.x; it < 256; it += G) outg_item(p, it);
}

// =================== fallback: same items as 6 ordinary kernels ===================
__global__ void __launch_bounds__(256) prep_f(Params p) {
    __shared__ __align__(16) unsigned short lds[2112];
    prep_item(p, blockIdx.x, lds);
}
__global__ void __launch_bounds__(256) qkva_f(Params p) { qkva_item(p, blockIdx.x); }
__global__ void __launch_bounds__(256) phtv_f(Params p) {
    __shared__ __align__(16) unsigned short lds[2112];
    phtv_item(p, blockIdx.x, lds);
}
__global__ void __launch_bounds__(256) attm_f(Params p) {
    __shared__ __align__(16) unsigned short lds[2112];
    attm_item(p, blockIdx.x, lds);
}
__global__ void __launch_bounds__(256) redln_f(Params p) {
    __shared__ __align__(16) unsigned short lds[2112];
    redln_item(p, blockIdx.x, lds);
}
__global__ void __launch_bounds__(256) outg_f(Params p) { outg_item(p, blockIdx.x); }

extern "C" void kernel_launch(void* const* d_in, const int* in_sizes, int n_in,
                              void* d_out, int out_size, void* d_ws, size_t ws_size,
                              hipStream_t stream)
{
    char* wsb = (char*)d_ws;
    Params p;
    p.x     = (const float*)d_in[0];
    p.ke_w1 = (const float*)d_in[1];  p.ke_b1 = (const float*)d_in[2];
    p.ke_w2 = (const float*)d_in[3];  p.ke_b2 = (const float*)d_in[4];
    p.qe_w1 = (const float*)d_in[5];  p.qe_b1 = (const float*)d_in[6];
    p.qe_w2 = (const float*)d_in[7];  p.qe_b2 = (const float*)d_in[8];
    p.amp_w = (const float*)d_in[9];  p.amp_b = (const float*)d_in[10];
    p.v_w   = (const float*)d_in[11]; p.v_b   = (const float*)d_in[12];
    p.ln_g  = (const float*)d_in[13]; p.ln_b  = (const float*)d_in[14];
    p.out_w = (const float*)d_in[15]; p.out_b = (const float*)d_in[16];
    p.out   = (float*)d_out;

    p.xb    = (unsigned short*)(wsb + 0);
    p.hk    = (unsigned short*)(wsb + 2097152);
    p.hq    = (unsigned short*)(wsb + 4194304);
    p.Vb    = (unsigned short*)(wsb + 6291456);
    p.Vt    = (unsigned short*)(wsb + 8388608);
    p.Qp    = (unsigned short*)(wsb + 10485760);
    p.Kp    = (unsigned short*)(wsb + 11010048);
    p.amp   = (float*)(wsb + 11534336);
    p.rnb   = (unsigned short*)(wsb + 12058624);
    p.wtke1 = (unsigned short*)(wsb + 14155776);
    p.wtqe1 = (unsigned short*)(wsb + 14680064);
    p.wtv   = (unsigned short*)(wsb + 15204352);
    p.wtout = (unsigned short*)(wsb + 15728640);
    p.wtke2 = (unsigned short*)(wsb + 16252928);
    p.wtqe2 = (unsigned short*)(wsb + 16318464);
    p.wtamp = (unsigned short*)(wsb + 16384000);
    p.P     = (unsigned short*)(wsb + 16449536);

    const size_t base_bytes = 16449536ull;
    const size_t per_group  = 2097152ull;
    int ng = 1;
    if (ws_size > base_bytes + per_group) {
        size_t n = (ws_size - base_bytes) / per_group;
        ng = (n > 8) ? 8 : (int)n;
        if (ng < 1) ng = 1;
    }
    p.ng = ng;

    // Decide cooperative vs fallback deterministically (same result every call).
    int occ = 0;
    hipError_t qe = hipOccupancyMaxActiveBlocksPerMultiprocessor(
        &occ, reinterpret_cast<const void*>(mega_k), 256, 0);
    bool coop = (qe == hipSuccess) && (occ >= 1);
    if (coop) {
        int grid = (occ >= 2) ? 512 : 256;
        void* args[] = { &p };
        hipError_t le = hipLaunchCooperativeKernel(
            reinterpret_cast<const void*>(mega_k), dim3(grid), dim3(256), args, 0, stream);
        if (le != hipSuccess) { (void)hipGetLastError(); coop = false; }
    }
    if (!coop) {
        prep_f<<<dim3(1376), dim3(256), 0, stream>>>(p);
        qkva_f<<<dim3(800), dim3(256), 0, stream>>>(p);
        phtv_f<<<dim3(1152), dim3(256), 0, stream>>>(p);
        attm_f<<<dim3(p.ng * 64), dim3(256), 0, stream>>>(p);
        redln_f<<<dim3(2048), dim3(256), 0, stream>>>(p);
        outg_f<<<dim3(256), dim3(256), 0, stream>>>(p);
    }
}